// Round 1
// baseline (750.942 us; speedup 1.0000x reference)
//
#include <hip/hip_runtime.h>
#include <math.h>

#define L      1024
#define BATCH  2
#define DM     1024
#define DCKV   256
#define DCQ    512
#define NH     8
#define DH     64
#define DR     32
#define NIH    4
#define KTS    96
#define LWIN   64

__device__ __forceinline__ float softplusf(float x) {
  // matches jax.nn.softplus = logaddexp(x, 0)
  return fmaxf(x, 0.f) + log1pf(expf(-fabsf(x)));
}

// ---------------- generic fp32 GEMM: C[M,N] = A[M,K] @ B[K,N] ----------------
// 64x64 tile, 256 threads, 4x4 per thread. M % 64 == 0, K % 16 == 0, N % 32 == 0.
__global__ __launch_bounds__(256) void gemm64(
    const float* __restrict__ A, const float* __restrict__ Bw,
    float* __restrict__ C, int M, int N, int K) {
  __shared__ float As[16][68];
  __shared__ float Bs[16][68];
  const int tid = threadIdx.x;
  const int bm = blockIdx.y << 6;
  const int bn = blockIdx.x << 6;
  const int tx = tid & 15;
  const int ty = tid >> 4;
  const int am = tid >> 2;          // 0..63 (A tile row)
  const int ak = (tid & 3) << 2;    // 0,4,8,12 (A tile k)
  const int bk = tid >> 4;          // 0..15 (B tile k)
  const int bn4 = (tid & 15) << 2;  // 0..60 (B tile col)
  const bool bok = (bn + bn4) < N;
  float acc[4][4] = {};
  for (int k0 = 0; k0 < K; k0 += 16) {
    float4 av = *reinterpret_cast<const float4*>(A + (size_t)(bm + am) * K + k0 + ak);
    As[ak + 0][am] = av.x; As[ak + 1][am] = av.y;
    As[ak + 2][am] = av.z; As[ak + 3][am] = av.w;
    if (bok) {
      float4 bv = *reinterpret_cast<const float4*>(Bw + (size_t)(k0 + bk) * N + bn + bn4);
      Bs[bk][bn4 + 0] = bv.x; Bs[bk][bn4 + 1] = bv.y;
      Bs[bk][bn4 + 2] = bv.z; Bs[bk][bn4 + 3] = bv.w;
    }
    __syncthreads();
#pragma unroll
    for (int k = 0; k < 16; ++k) {
      float a0 = As[k][(ty << 2) + 0], a1 = As[k][(ty << 2) + 1];
      float a2 = As[k][(ty << 2) + 2], a3 = As[k][(ty << 2) + 3];
      float b0 = Bs[k][(tx << 2) + 0], b1 = Bs[k][(tx << 2) + 1];
      float b2 = Bs[k][(tx << 2) + 2], b3 = Bs[k][(tx << 2) + 3];
      acc[0][0] += a0 * b0; acc[0][1] += a0 * b1; acc[0][2] += a0 * b2; acc[0][3] += a0 * b3;
      acc[1][0] += a1 * b0; acc[1][1] += a1 * b1; acc[1][2] += a1 * b2; acc[1][3] += a1 * b3;
      acc[2][0] += a2 * b0; acc[2][1] += a2 * b1; acc[2][2] += a2 * b2; acc[2][3] += a2 * b3;
      acc[3][0] += a3 * b0; acc[3][1] += a3 * b1; acc[3][2] += a3 * b2; acc[3][3] += a3 * b3;
    }
    __syncthreads();
  }
#pragma unroll
  for (int i = 0; i < 4; ++i) {
    int r = bm + (ty << 2) + i;
#pragma unroll
    for (int j = 0; j < 4; ++j) {
      int c = bn + (tx << 2) + j;
      if (c < N) C[(size_t)r * N + c] = acc[i][j];
    }
  }
}

// ------------- LightningIndexer scores + TokenSelector top-k -----------------
// One block per (b,t). Reproduces jax.lax.top_k ordering exactly:
//   values desc, ties broken by smaller index.
// Structure: slots 0..63 = local window (all +inf, ascending s);
//            slots 64..  = top-min(32,nf) of finite region s in [0,t-64];
//            remainder   = causal -inf entries s = t+1, t+2, ... (ascending).
// For t < 64 the whole row degenerates to idx = [0..95].
__global__ __launch_bounds__(256) void indexer_topk(
    const float* __restrict__ qi, const float* __restrict__ ki,
    const float* __restrict__ idx_w, int* __restrict__ idx_sel) {
  const int bt = blockIdx.x;
  const int b = bt >> 10;
  const int t = bt & 1023;
  const int tid = threadIdx.x;
  int* out = idx_sel + (size_t)bt * KTS;
  if (t < LWIN) {
    if (tid < KTS) out[tid] = tid;
    return;
  }
  if (tid < 64) out[tid] = t - 63 + tid;
  const int nf = t - 63;  // finite candidates: s = 0 .. t-64
  __shared__ float qis[256];
  __shared__ float wsh[4];
  __shared__ unsigned long long keys[960];
  __shared__ unsigned long long wred[4];
  qis[tid] = qi[(size_t)bt * 256 + tid];
  if (tid < 4) wsh[tid] = idx_w[tid];
  __syncthreads();
  const float* kib = ki + (size_t)b * L * 64;
  for (int s = tid; s < nf; s += 256) {
    const float* kr = kib + (size_t)s * 64;
    float a0 = 0.f, a1 = 0.f, a2 = 0.f, a3 = 0.f;
#pragma unroll 8
    for (int d = 0; d < 64; ++d) {
      float kv = kr[d];
      a0 += qis[d] * kv;
      a1 += qis[64 + d] * kv;
      a2 += qis[128 + d] * kv;
      a3 += qis[192 + d] * kv;
    }
    float I = wsh[0] * fmaxf(a0, 0.f) + wsh[1] * fmaxf(a1, 0.f)
            + wsh[2] * fmaxf(a2, 0.f) + wsh[3] * fmaxf(a3, 0.f);
    unsigned ib = __float_as_uint(I);
    if (ib == 0x80000000u) ib = 0u;  // canonicalize -0.0 -> +0.0 (relu ties!)
    ib = (ib & 0x80000000u) ? ~ib : (ib | 0x80000000u);  // monotone mapping
    keys[s] = ((unsigned long long)ib << 32) |
              (unsigned long long)(0xFFFFFFFFu - (unsigned)s);
  }
  __syncthreads();
  const int topM = nf < 32 ? nf : 32;
  for (int it = 0; it < topM; ++it) {
    unsigned long long best = 0ull;
    for (int s = tid; s < nf; s += 256) {
      unsigned long long v = keys[s];
      if (v > best) best = v;
    }
    for (int off = 32; off > 0; off >>= 1) {
      unsigned long long o = __shfl_down(best, off);
      if (o > best) best = o;
    }
    if ((tid & 63) == 0) wred[tid >> 6] = best;
    __syncthreads();
    if (tid == 0) {
      unsigned long long m = wred[0];
      if (wred[1] > m) m = wred[1];
      if (wred[2] > m) m = wred[2];
      if (wred[3] > m) m = wred[3];
      unsigned s = 0xFFFFFFFFu - (unsigned)(m & 0xFFFFFFFFull);
      out[64 + it] = (int)s;
      keys[s] = 0ull;  // remove; all live keys are > 0
    }
    __syncthreads();
  }
  for (int j = tid; j < 32 - topM; j += 256) out[64 + topM + j] = t + 1 + j;
}

// ----------------------- sparse attention per (b,t) --------------------------
__global__ __launch_bounds__(256) void attn_kernel(
    const float* __restrict__ qc_all, const float* __restrict__ qr_pre,
    const float* __restrict__ kc, const float* __restrict__ vc,
    const float* __restrict__ kr_pre, const int* __restrict__ idx_sel,
    const float* __restrict__ raw_delta, float* __restrict__ attn_out) {
  const int bt = blockIdx.x;
  const int b = bt >> 10;
  const int t = bt & 1023;
  const int tid = threadIdx.x;

  __shared__ __align__(16) float qcs[NH * DH];   // 512
  __shared__ __align__(16) float qrs[NH * DR];   // 256
  __shared__ __align__(16) float krs[KTS * DR];  // 3072
  __shared__ float scores[NH][KTS];
  __shared__ int sel[KTS];
  __shared__ float thetav[16], deltav[16];
  __shared__ float mu[NH * DR];

  qcs[tid] = qc_all[(size_t)bt * 512 + tid];
  qcs[256 + tid] = qc_all[(size_t)bt * 512 + 256 + tid];
  if (tid < KTS) sel[tid] = idx_sel[(size_t)bt * KTS + tid];
  if (tid < 16) {
    thetav[tid] = (float)(1.0 / pow(10000.0, (double)tid / 16.0));
    float r = raw_delta[tid];
    deltav[tid] = -6.2831853071795864769f * (1.f / (1.f + expf(-r)));
  }
  mu[tid] = softplusf(qr_pre[(size_t)bt * 256 + tid]);
  __syncthreads();

  // q_r = PoPE(qr_pre, angle = t*theta + delta), per head
  if (tid < 128) {
    int h = tid >> 4, i = tid & 15;
    float ang = (float)t * thetav[i] + deltav[i];
    float c = cosf(ang), s = sinf(ang);
    float m1 = mu[h * DR + i], m2 = mu[h * DR + 16 + i];
    qrs[h * DR + i] = m1 * c - m2 * s;
    qrs[h * DR + 16 + i] = m1 * s + m2 * c;
  }
  // key_r = PoPE(kr_pre[sel[k]], angle = k*theta + delta) -- angle uses SLOT k
  for (int e = tid; e < KTS * 16; e += 256) {
    int k = e >> 4, i = e & 15;
    int s = sel[k];
    float x1 = kr_pre[(size_t)(b * L + s) * DR + i];
    float x2 = kr_pre[(size_t)(b * L + s) * DR + 16 + i];
    float m1 = softplusf(x1), m2 = softplusf(x2);
    float ang = (float)k * thetav[i] + deltav[i];
    float c = cosf(ang), sn = sinf(ang);
    krs[k * DR + i] = m1 * c - m2 * sn;
    krs[k * DR + 16 + i] = m1 * sn + m2 * c;
  }
  __syncthreads();

  const float scale = 0.10206207261596575f;  // (64+32)^-0.5
  for (int e = tid; e < NH * KTS; e += 256) {
    int h = e / KTS, k = e - h * KTS;
    int s = sel[k];
    const float4* kc4 = reinterpret_cast<const float4*>(kc + (size_t)(b * L + s) * 512 + h * 64);
    const float4* qc4 = reinterpret_cast<const float4*>(&qcs[h * 64]);
    float acc = 0.f;
#pragma unroll
    for (int d = 0; d < 16; ++d) {
      float4 kv = kc4[d], qv = qc4[d];
      acc += qv.x * kv.x + qv.y * kv.y + qv.z * kv.z + qv.w * kv.w;
    }
    const float4* kr4 = reinterpret_cast<const float4*>(&krs[k * DR]);
    const float4* qr4 = reinterpret_cast<const float4*>(&qrs[h * DR]);
#pragma unroll
    for (int d = 0; d < 8; ++d) {
      float4 kv = kr4[d], qv = qr4[d];
      acc += qv.x * kv.x + qv.y * kv.y + qv.z * kv.z + qv.w * kv.w;
    }
    scores[h][k] = acc * scale;
  }
  __syncthreads();
  if (tid < NH) {
    float mx = -1e30f;
    for (int k = 0; k < KTS; ++k) mx = fmaxf(mx, scores[tid][k]);
    float sum = 0.f;
    for (int k = 0; k < KTS; ++k) {
      float e = expf(scores[tid][k] - mx);
      scores[tid][k] = e;
      sum += e;
    }
    float inv = 1.f / sum;
    for (int k = 0; k < KTS; ++k) scores[tid][k] *= inv;
  }
  __syncthreads();
  for (int e = tid; e < NH * DH; e += 256) {
    int h = e >> 6, d = e & 63;
    float acc = 0.f;
    for (int k = 0; k < KTS; ++k)
      acc += scores[h][k] * vc[(size_t)(b * L + sel[k]) * 512 + h * 64 + d];
    attn_out[(size_t)bt * 512 + e] = acc;
  }
}

// -----------------------------------------------------------------------------
extern "C" void kernel_launch(void* const* d_in, const int* in_sizes, int n_in,
                              void* d_out, int out_size, void* d_ws, size_t ws_size,
                              hipStream_t stream) {
  const float* x      = (const float*)d_in[0];
  const float* W_dkv  = (const float*)d_in[1];
  const float* W_uk   = (const float*)d_in[2];
  const float* W_uv   = (const float*)d_in[3];
  const float* W_dq   = (const float*)d_in[4];
  const float* W_uq   = (const float*)d_in[5];
  const float* W_qr   = (const float*)d_in[6];
  const float* W_kr   = (const float*)d_in[7];
  const float* W_out  = (const float*)d_in[8];
  const float* idx_wq = (const float*)d_in[9];
  const float* idx_wk = (const float*)d_in[10];
  const float* idx_w  = (const float*)d_in[11];
  const float* raw_dl = (const float*)d_in[12];
  float* out = (float*)d_out;
  float* ws = (float*)d_ws;

  const int M = BATCH * L;  // 2048
  float* c_kv = ws;                    // 2048*256
  float* c_q  = c_kv + 2048 * 256;     // 2048*512
  float* kc   = c_q + 2048 * 512;      // 2048*512
  float* vc   = kc + 2048 * 512;       // 2048*512
  float* qc   = vc + 2048 * 512;       // 2048*512
  float* qrp  = qc + 2048 * 512;       // 2048*256
  float* qi   = qrp + 2048 * 256;      // 2048*256
  float* ki   = qi + 2048 * 256;       // 2048*64
  float* krp  = ki + 2048 * 64;        // 2048*32
  float* ao   = krp + 2048 * 32;       // 2048*512
  int* sel    = (int*)(ao + 2048 * 512);  // 2048*96 ints

  dim3 blk(256);
  auto g = [](int n, int m) { return dim3((n + 63) / 64, (m + 63) / 64); };

  hipLaunchKernelGGL(gemm64, g(256, M),  blk, 0, stream, x, W_dkv,  c_kv, M, 256,  1024);
  hipLaunchKernelGGL(gemm64, g(512, M),  blk, 0, stream, x, W_dq,   c_q,  M, 512,  1024);
  hipLaunchKernelGGL(gemm64, g(256, M),  blk, 0, stream, x, idx_wq, qi,   M, 256,  1024);
  hipLaunchKernelGGL(gemm64, g(64, M),   blk, 0, stream, x, idx_wk, ki,   M, 64,   1024);
  hipLaunchKernelGGL(gemm64, g(32, M),   blk, 0, stream, x, W_kr,   krp,  M, 32,   1024);
  hipLaunchKernelGGL(gemm64, g(512, M),  blk, 0, stream, c_kv, W_uk, kc,  M, 512,  256);
  hipLaunchKernelGGL(gemm64, g(512, M),  blk, 0, stream, c_kv, W_uv, vc,  M, 512,  256);
  hipLaunchKernelGGL(gemm64, g(512, M),  blk, 0, stream, c_q,  W_uq, qc,  M, 512,  512);
  hipLaunchKernelGGL(gemm64, g(256, M),  blk, 0, stream, c_q,  W_qr, qrp, M, 256,  512);
  hipLaunchKernelGGL(indexer_topk, dim3(M), blk, 0, stream, qi, ki, idx_w, sel);
  hipLaunchKernelGGL(attn_kernel, dim3(M), blk, 0, stream, qc, qrp, kc, vc, krp, sel, raw_dl, ao);
  hipLaunchKernelGGL(gemm64, g(1024, M), blk, 0, stream, ao, W_out, out, M, 1024, 512);
}

// Round 2
// 483.682 us; speedup vs baseline: 1.5526x; 1.5526x over previous
//
#include <hip/hip_runtime.h>
#include <math.h>

#define L      1024
#define BATCH  2
#define DM     1024
#define NH     8
#define DH     64
#define DR     32
#define KTS    96
#define LWIN   64

// fused buffer widths
#define NXP    1120   // [c_kv(256) | c_q(512) | qi(256) | ki(64) | krp(32)]
#define NKV    1024   // [kc(512) | vc(512)]
#define NQP    768    // [qc(512) | qrp(256)]

__device__ __forceinline__ float softplusf(float x) {
  return fmaxf(x, 0.f) + log1pf(expf(-fabsf(x)));
}

// --------------- weight concatenation (column-wise) --------------------------
__global__ __launch_bounds__(256) void concat_weights(
    const float* __restrict__ W_dkv, const float* __restrict__ W_dq,
    const float* __restrict__ idx_wq, const float* __restrict__ idx_wk,
    const float* __restrict__ W_kr, const float* __restrict__ W_uk,
    const float* __restrict__ W_uv, const float* __restrict__ W_uq,
    const float* __restrict__ W_qr,
    float* __restrict__ Bx, float* __restrict__ Bkv, float* __restrict__ Bq) {
  const int T1 = 1024 * (NXP / 4);  // float4 counts
  const int T2 = 256 * (NKV / 4);
  const int T3 = 512 * (NQP / 4);
  for (int i = blockIdx.x * 256 + threadIdx.x; i < T1 + T2 + T3;
       i += gridDim.x * 256) {
    if (i < T1) {
      int r = i / (NXP / 4), col = (i % (NXP / 4)) * 4;
      float4 v;
      if (col < 256)       v = *(const float4*)(W_dkv + (size_t)r * 256 + col);
      else if (col < 768)  v = *(const float4*)(W_dq + (size_t)r * 512 + (col - 256));
      else if (col < 1024) v = *(const float4*)(idx_wq + (size_t)r * 256 + (col - 768));
      else if (col < 1088) v = *(const float4*)(idx_wk + (size_t)r * 64 + (col - 1024));
      else                 v = *(const float4*)(W_kr + (size_t)r * 32 + (col - 1088));
      *(float4*)(Bx + (size_t)r * NXP + col) = v;
    } else if (i < T1 + T2) {
      int j = i - T1;
      int r = j / (NKV / 4), col = (j % (NKV / 4)) * 4;
      float4 v = (col < 512) ? *(const float4*)(W_uk + (size_t)r * 512 + col)
                             : *(const float4*)(W_uv + (size_t)r * 512 + (col - 512));
      *(float4*)(Bkv + (size_t)r * NKV + col) = v;
    } else {
      int j = i - T1 - T2;
      int r = j / (NQP / 4), col = (j % (NQP / 4)) * 4;
      float4 v = (col < 512) ? *(const float4*)(W_uq + (size_t)r * 512 + col)
                             : *(const float4*)(W_qr + (size_t)r * 256 + (col - 512));
      *(float4*)(Bq + (size_t)r * NQP + col) = v;
    }
  }
}

// ---------------- fp32 GEMM: C[M,N] = A[M,K] @ B[K,N] ------------------------
// 128x64 tile, 256 threads, 8x4 per thread. M%128==0, K%16==0, N%4==0.
__global__ __launch_bounds__(256) void gemm128(
    const float* __restrict__ A, int lda, const float* __restrict__ B,
    float* __restrict__ C, int M, int N, int K) {
  __shared__ float As[16][132];
  __shared__ float Bs[16][68];
  const int tid = threadIdx.x;
  const int bm = blockIdx.y * 128;
  const int bn = blockIdx.x * 64;
  const int ty = tid >> 4, tx = tid & 15;
  const int arow = tid >> 1, ak = (tid & 1) * 8;
  const int bk = tid >> 4, bn4 = (tid & 15) * 4;
  const bool bok = (bn + bn4) < N;
  float acc[8][4] = {};
  for (int k0 = 0; k0 < K; k0 += 16) {
    const float* ap = A + (size_t)(bm + arow) * lda + k0 + ak;
    float4 av0 = *(const float4*)(ap);
    float4 av1 = *(const float4*)(ap + 4);
    float4 bv = make_float4(0.f, 0.f, 0.f, 0.f);
    if (bok) bv = *(const float4*)(B + (size_t)(k0 + bk) * N + bn + bn4);
    As[ak + 0][arow] = av0.x; As[ak + 1][arow] = av0.y;
    As[ak + 2][arow] = av0.z; As[ak + 3][arow] = av0.w;
    As[ak + 4][arow] = av1.x; As[ak + 5][arow] = av1.y;
    As[ak + 6][arow] = av1.z; As[ak + 7][arow] = av1.w;
    Bs[bk][bn4 + 0] = bv.x; Bs[bk][bn4 + 1] = bv.y;
    Bs[bk][bn4 + 2] = bv.z; Bs[bk][bn4 + 3] = bv.w;
    __syncthreads();
#pragma unroll
    for (int k = 0; k < 16; ++k) {
      float4 a0 = *(const float4*)&As[k][ty * 8];
      float4 a1 = *(const float4*)&As[k][ty * 8 + 4];
      float4 b = *(const float4*)&Bs[k][tx * 4];
      float a[8] = {a0.x, a0.y, a0.z, a0.w, a1.x, a1.y, a1.z, a1.w};
      float bb[4] = {b.x, b.y, b.z, b.w};
#pragma unroll
      for (int i = 0; i < 8; ++i)
#pragma unroll
        for (int j = 0; j < 4; ++j) acc[i][j] += a[i] * bb[j];
    }
    __syncthreads();
  }
  if (bok) {
#pragma unroll
    for (int i = 0; i < 8; ++i) {
      float4 v = make_float4(acc[i][0], acc[i][1], acc[i][2], acc[i][3]);
      *(float4*)(C + (size_t)(bm + ty * 8 + i) * N + bn + tx * 4) = v;
    }
  }
}

// ------------- LightningIndexer scores + TokenSelector top-k -----------------
// qi = xproj cols [768,1024), ki = xproj cols [1024,1088), ld = NXP
__global__ __launch_bounds__(256) void indexer_topk(
    const float* __restrict__ xproj, const float* __restrict__ idx_w,
    int* __restrict__ idx_sel) {
  const int bt = blockIdx.x;
  const int b = bt >> 10;
  const int t = bt & 1023;
  const int tid = threadIdx.x;
  int* out = idx_sel + (size_t)bt * KTS;
  if (t < LWIN) {
    if (tid < KTS) out[tid] = tid;
    return;
  }
  if (tid < 64) out[tid] = t - 63 + tid;
  const int nf = t - 63;
  __shared__ float qis[256];
  __shared__ float wsh[4];
  __shared__ unsigned long long keys[960];
  __shared__ unsigned long long wred[4];
  qis[tid] = xproj[(size_t)bt * NXP + 768 + tid];
  if (tid < 4) wsh[tid] = idx_w[tid];
  __syncthreads();
  const float* kib = xproj + (size_t)b * L * NXP + 1024;
  for (int s = tid; s < nf; s += 256) {
    const float* kr = kib + (size_t)s * NXP;
    float a0 = 0.f, a1 = 0.f, a2 = 0.f, a3 = 0.f;
#pragma unroll 8
    for (int d = 0; d < 64; ++d) {
      float kv = kr[d];
      a0 += qis[d] * kv;
      a1 += qis[64 + d] * kv;
      a2 += qis[128 + d] * kv;
      a3 += qis[192 + d] * kv;
    }
    float I = wsh[0] * fmaxf(a0, 0.f) + wsh[1] * fmaxf(a1, 0.f)
            + wsh[2] * fmaxf(a2, 0.f) + wsh[3] * fmaxf(a3, 0.f);
    unsigned ib = __float_as_uint(I);
    if (ib == 0x80000000u) ib = 0u;
    ib = (ib & 0x80000000u) ? ~ib : (ib | 0x80000000u);
    keys[s] = ((unsigned long long)ib << 32) |
              (unsigned long long)(0xFFFFFFFFu - (unsigned)s);
  }
  __syncthreads();
  const int topM = nf < 32 ? nf : 32;
  for (int it = 0; it < topM; ++it) {
    unsigned long long best = 0ull;
    for (int s = tid; s < nf; s += 256) {
      unsigned long long v = keys[s];
      if (v > best) best = v;
    }
    for (int off = 32; off > 0; off >>= 1) {
      unsigned long long o = __shfl_down(best, off);
      if (o > best) best = o;
    }
    if ((tid & 63) == 0) wred[tid >> 6] = best;
    __syncthreads();
    if (tid == 0) {
      unsigned long long m = wred[0];
      if (wred[1] > m) m = wred[1];
      if (wred[2] > m) m = wred[2];
      if (wred[3] > m) m = wred[3];
      unsigned s = 0xFFFFFFFFu - (unsigned)(m & 0xFFFFFFFFull);
      out[64 + it] = (int)s;
      keys[s] = 0ull;
    }
    __syncthreads();
  }
  for (int j = tid; j < 32 - topM; j += 256) out[64 + topM + j] = t + 1 + j;
}

// ----------------------- sparse attention per (b,t) --------------------------
// qproj row: [qc(512) | qrp(256)]; kvproj row: [kc(512) | vc(512)];
// kr_pre = xproj cols [1088,1120)
__global__ __launch_bounds__(256) void attn_kernel(
    const float* __restrict__ qproj, const float* __restrict__ kvproj,
    const float* __restrict__ xproj, const int* __restrict__ idx_sel,
    const float* __restrict__ raw_delta, float* __restrict__ attn_out) {
  const int bt = blockIdx.x;
  const int b = bt >> 10;
  const int t = bt & 1023;
  const int tid = threadIdx.x;

  __shared__ __align__(16) float qcs[NH * DH];   // 512
  __shared__ __align__(16) float qrs[NH * DR];   // 256
  __shared__ __align__(16) float krs[KTS * DR];  // 3072
  __shared__ float scoresS[NH][KTS];
  __shared__ int selS[KTS];
  __shared__ float thetav[16], deltav[16];
  __shared__ float mu[NH * DR];

  const float* qrow = qproj + (size_t)bt * NQP;
  qcs[tid] = qrow[tid];
  qcs[256 + tid] = qrow[256 + tid];
  mu[tid] = softplusf(qrow[512 + tid]);
  if (tid < KTS) selS[tid] = idx_sel[(size_t)bt * KTS + tid];
  if (tid < 16) {
    thetav[tid] = (float)(1.0 / pow(10000.0, (double)tid / 16.0));
    float r = raw_delta[tid];
    deltav[tid] = -6.2831853071795864769f * (1.f / (1.f + expf(-r)));
  }
  __syncthreads();

  if (tid < 128) {
    int h = tid >> 4, i = tid & 15;
    float ang = (float)t * thetav[i] + deltav[i];
    float c = cosf(ang), s = sinf(ang);
    float m1 = mu[h * DR + i], m2 = mu[h * DR + 16 + i];
    qrs[h * DR + i] = m1 * c - m2 * s;
    qrs[h * DR + 16 + i] = m1 * s + m2 * c;
  }
  const float* krb = xproj + (size_t)b * L * NXP + 1088;
  for (int e = tid; e < KTS * 16; e += 256) {
    int k = e >> 4, i = e & 15;
    int s = selS[k];
    float x1 = krb[(size_t)s * NXP + i];
    float x2 = krb[(size_t)s * NXP + 16 + i];
    float m1 = softplusf(x1), m2 = softplusf(x2);
    float ang = (float)k * thetav[i] + deltav[i];
    float c = cosf(ang), sn = sinf(ang);
    krs[k * DR + i] = m1 * c - m2 * sn;
    krs[k * DR + 16 + i] = m1 * sn + m2 * c;
  }
  __syncthreads();

  // ---- scores: k-major, block-coalesced K-row loads, shfl reduce ----
  const float scale = 0.10206207261596575f;  // (64+32)^-0.5
  const int h = tid >> 5;   // 32 threads per head
  const int l = tid & 31;
  const float2 qv = *(const float2*)&qcs[h * DH + 2 * l];
  float2 qr2 = make_float2(0.f, 0.f);
  if (l < 16) qr2 = *(const float2*)&qrs[h * DR + 2 * l];
  const float* kvb = kvproj + (size_t)b * L * NKV;
#pragma unroll 4
  for (int k = 0; k < KTS; ++k) {
    const float2 kv = *(const float2*)(kvb + (size_t)selS[k] * NKV + 2 * tid);
    float p = qv.x * kv.x + qv.y * kv.y;
    if (l < 16) {
      const float2 kr2 = *(const float2*)&krs[k * DR + 2 * l];
      p += qr2.x * kr2.x + qr2.y * kr2.y;
    }
#pragma unroll
    for (int off = 16; off > 0; off >>= 1) p += __shfl_xor(p, off, 32);
    if (l == 0) scoresS[h][k] = p * scale;
  }
  __syncthreads();

  // ---- softmax: each 32-lane group owns one head ----
  {
    float s0 = scoresS[h][l], s1 = scoresS[h][l + 32], s2 = scoresS[h][l + 64];
    float mx = fmaxf(fmaxf(s0, s1), s2);
#pragma unroll
    for (int off = 16; off > 0; off >>= 1) mx = fmaxf(mx, __shfl_xor(mx, off, 32));
    float e0 = expf(s0 - mx), e1 = expf(s1 - mx), e2 = expf(s2 - mx);
    float sum = e0 + e1 + e2;
#pragma unroll
    for (int off = 16; off > 0; off >>= 1) sum += __shfl_xor(sum, off, 32);
    float inv = 1.f / sum;
    scoresS[h][l] = e0 * inv;
    scoresS[h][l + 32] = e1 * inv;
    scoresS[h][l + 64] = e2 * inv;
  }
  __syncthreads();

  // ---- PV: coalesced V-row loads, broadcast weights ----
  float2 acc = make_float2(0.f, 0.f);
#pragma unroll 4
  for (int k = 0; k < KTS; ++k) {
    const float2 v = *(const float2*)(kvb + (size_t)selS[k] * NKV + 512 + 2 * tid);
    const float w = scoresS[h][k];
    acc.x += w * v.x;
    acc.y += w * v.y;
  }
  *(float2*)(attn_out + (size_t)bt * 512 + 2 * tid) = acc;
}

// -----------------------------------------------------------------------------
extern "C" void kernel_launch(void* const* d_in, const int* in_sizes, int n_in,
                              void* d_out, int out_size, void* d_ws, size_t ws_size,
                              hipStream_t stream) {
  const float* x      = (const float*)d_in[0];
  const float* W_dkv  = (const float*)d_in[1];
  const float* W_uk   = (const float*)d_in[2];
  const float* W_uv   = (const float*)d_in[3];
  const float* W_dq   = (const float*)d_in[4];
  const float* W_uq   = (const float*)d_in[5];
  const float* W_qr   = (const float*)d_in[6];
  const float* W_kr   = (const float*)d_in[7];
  const float* W_out  = (const float*)d_in[8];
  const float* idx_wq = (const float*)d_in[9];
  const float* idx_wk = (const float*)d_in[10];
  const float* idx_w  = (const float*)d_in[11];
  const float* raw_dl = (const float*)d_in[12];
  float* out = (float*)d_out;
  float* ws = (float*)d_ws;

  const int M = BATCH * L;  // 2048
  float* Bx     = ws;                        // 1024*1120
  float* Bkv    = Bx + 1024 * NXP;           // 256*1024
  float* Bq     = Bkv + 256 * NKV;           // 512*768
  float* xproj  = Bq + 512 * NQP;            // 2048*1120
  float* kvproj = xproj + (size_t)M * NXP;   // 2048*1024
  float* qproj  = kvproj + (size_t)M * NKV;  // 2048*768
  float* ao     = qproj + (size_t)M * NQP;   // 2048*512
  int* sel      = (int*)(ao + (size_t)M * 512);

  dim3 blk(256);
  hipLaunchKernelGGL(concat_weights, dim3(1024), blk, 0, stream,
                     W_dkv, W_dq, idx_wq, idx_wk, W_kr, W_uk, W_uv, W_uq, W_qr,
                     Bx, Bkv, Bq);
  hipLaunchKernelGGL(gemm128, dim3((NXP + 63) / 64, M / 128), blk, 0, stream,
                     x, DM, Bx, xproj, M, NXP, DM);
  hipLaunchKernelGGL(indexer_topk, dim3(M), blk, 0, stream, xproj, idx_w, sel);
  hipLaunchKernelGGL(gemm128, dim3(NKV / 64, M / 128), blk, 0, stream,
                     xproj, NXP, Bkv, kvproj, M, NKV, 256);
  hipLaunchKernelGGL(gemm128, dim3(NQP / 64, M / 128), blk, 0, stream,
                     xproj + 256, NXP, Bq, qproj, M, NQP, 512);
  hipLaunchKernelGGL(attn_kernel, dim3(M), blk, 0, stream,
                     qproj, kvproj, xproj, sel, raw_dl, ao);
  hipLaunchKernelGGL(gemm128, dim3(1024 / 64, M / 128), blk, 0, stream,
                     ao, 512, W_out, out, M, 1024, 512);
}